// Round 12
// baseline (314.583 us; speedup 1.0000x reference)
//
#include <hip/hip_runtime.h>

// Problem constants (from reference setup_inputs): B=8, L=4096, D=256, f32.
#define BATCH 8
#define SEQ   4096
#define DIM   256

typedef float floatx2 __attribute__((ext_vector_type(2)));
typedef float floatx4 __attribute__((ext_vector_type(4)));

// ---------------------------------------------------------------------------
// Single-pass decoupled-lookback scan.
//   tile (b,j): T=16 timesteps. One block per tile, 256 threads = 256 cols.
//   ws layout: [0,8KB) flags (1 uint/tile), [8KB,8KB+4) ticket,
//              [16KB, +8MB) vals_agg, [16KB+8MB, +8MB) vals_inc
//              (payload = 2x u64 per column: (pr,pi),(yr,yi))
//   flags/ticket zeroed per launch via hipMemsetAsync (replay-safe).
//   Ticket is j-major so all BATCH chains advance together; ticket order =
//   residency order => tile j only waits on tiles that started earlier =>
//   deadlock-free. Payload uses agent-scope relaxed atomics (cache-bypass,
//   XCD-safe); flag uses release/acquire.
// ---------------------------------------------------------------------------
constexpr int NT_MAIN = 256;
constexpr int T_MAIN  = SEQ / NT_MAIN;            // 16
constexpr int NTILES  = BATCH * NT_MAIN;          // 2048
constexpr size_t WS_HDR  = 16384;
constexpr size_t WS_VALS = (size_t)NTILES * DIM * 16;   // 8 MB per buffer
constexpr size_t WS_NEED = WS_HDR + 2 * WS_VALS;

__device__ __forceinline__ unsigned long long pack2f(float a, float b) {
    union { float f[2]; unsigned long long u; } u_;
    u_.f[0] = a; u_.f[1] = b; return u_.u;
}
__device__ __forceinline__ void unpack2f(unsigned long long u, float& a, float& b) {
    union { unsigned long long u; float f[2]; } u_;
    u_.u = u; a = u_.f[0]; b = u_.f[1];
}

__global__ __launch_bounds__(256) void k_scan_lookback(
    const float* __restrict__ Ar, const float* __restrict__ Ai,
    const float* __restrict__ Xr, const float* __restrict__ Xi,
    float* __restrict__ outf,
    unsigned* __restrict__ flags, unsigned* __restrict__ ticket,
    unsigned long long* __restrict__ vagg, unsigned long long* __restrict__ vinc)
{
    constexpr int T = T_MAIN, NT = NT_MAIN;
    constexpr int TILE_FLOATS = T * DIM;           // 4096 floats / array
    __shared__ float lds[4 * TILE_FLOATS];         // 64 KB
    __shared__ unsigned s_bcast;

    // Dispatch-order ticket (ignore blockIdx entirely).
    if (threadIdx.x == 0) s_bcast = atomicAdd(ticket, 1u);
    __syncthreads();
    unsigned tk = s_bcast;
    int j = tk / BATCH;
    int b = tk % BATCH;
    int tile = b * NT + j;

    // ---- stage 64KB tile into LDS (R11 form, proven conflict-free) ----
    int wave = threadIdx.x >> 6, lane = threadIdx.x & 63;
    size_t tile_off = ((size_t)b * SEQ + (size_t)j * T) * DIM;
    const float* src = (wave == 0) ? Ar : (wave == 1) ? Ai : (wave == 2) ? Xr : Xi;
    const float* gsrc = src + tile_off + (size_t)lane * 4;
    float* lbase = &lds[wave * TILE_FLOATS];
#pragma unroll
    for (int s = 0; s < T; ++s) {
        __builtin_amdgcn_global_load_lds(
            (const __attribute__((address_space(1))) void*)(gsrc + s * DIM),
            (__attribute__((address_space(3))) void*)(lbase + s * DIM),
            16, 0, 0);
    }
    __syncthreads();   // vmcnt(0) drain + barrier

    // ---- local aggregate for column d: product chain + y-from-zero ----
    int d = threadIdx.x;
    float pr = 1.f, pi = 0.f, yr = 0.f, yi = 0.f;
#pragma unroll
    for (int t = 0; t < T; ++t) {
        float a_r = lds[0 * TILE_FLOATS + t * DIM + d];
        float a_i = lds[1 * TILE_FLOATS + t * DIM + d];
        float x_r = lds[2 * TILE_FLOATS + t * DIM + d];
        float x_i = lds[3 * TILE_FLOATS + t * DIM + d];
        float npr = a_r * pr - a_i * pi;
        float npi = a_r * pi + a_i * pr;
        pr = npr; pi = npi;
        float nyr = a_r * yr - a_i * yi + x_r;
        float nyi = a_r * yi + a_i * yr + x_i;
        yr = nyr; yi = nyi;
    }

    size_t vslot = 2 * ((size_t)tile * DIM + d);
    float sy_r, sy_i;      // incoming y for this tile (prefix x-part)

    if (j == 0) {
        // inclusive == own aggregate; prefix = identity
        __hip_atomic_store(&vinc[vslot + 0], pack2f(pr, pi), __ATOMIC_RELAXED, __HIP_MEMORY_SCOPE_AGENT);
        __hip_atomic_store(&vinc[vslot + 1], pack2f(yr, yi), __ATOMIC_RELAXED, __HIP_MEMORY_SCOPE_AGENT);
        __syncthreads();   // all payload stores complete (vmcnt drained)
        if (threadIdx.x == 0)
            __hip_atomic_store(&flags[tile], 2u, __ATOMIC_RELEASE, __HIP_MEMORY_SCOPE_AGENT);
        sy_r = 0.f; sy_i = 0.f;
    } else {
        // publish aggregate ASAP to unblock successors
        __hip_atomic_store(&vagg[vslot + 0], pack2f(pr, pi), __ATOMIC_RELAXED, __HIP_MEMORY_SCOPE_AGENT);
        __hip_atomic_store(&vagg[vslot + 1], pack2f(yr, yi), __ATOMIC_RELAXED, __HIP_MEMORY_SCOPE_AGENT);
        __syncthreads();
        if (threadIdx.x == 0)
            __hip_atomic_store(&flags[tile], 1u, __ATOMIC_RELEASE, __HIP_MEMORY_SCOPE_AGENT);

        // walk back, composing accum = tiles (k+1 .. j-1); stop at inclusive
        float car = 1.f, cai = 0.f, cxr = 0.f, cxi = 0.f;
        int k = j - 1;
        for (;;) {
            if (threadIdx.x == 0) {
                unsigned f;
                do {
                    f = __hip_atomic_load(&flags[b * NT + k], __ATOMIC_ACQUIRE, __HIP_MEMORY_SCOPE_AGENT);
                    if (!f) __builtin_amdgcn_s_sleep(1);
                } while (!f);
                s_bcast = f;
            }
            __syncthreads();
            unsigned f = s_bcast;
            __syncthreads();   // allow s_bcast reuse next iteration

            size_t ps = 2 * ((size_t)(b * NT + k) * DIM + d);
            const unsigned long long* vb = (f == 2u) ? vinc : vagg;
            unsigned long long w0 = __hip_atomic_load(&vb[ps + 0], __ATOMIC_RELAXED, __HIP_MEMORY_SCOPE_AGENT);
            unsigned long long w1 = __hip_atomic_load(&vb[ps + 1], __ATOMIC_RELAXED, __HIP_MEMORY_SCOPE_AGENT);
            float var, vai, vxr, vxi;
            unpack2f(w0, var, vai);
            unpack2f(w1, vxr, vxi);
            // accum_new = combine(earlier=v, later=accum):
            //   a = a_acc * a_v ; x = a_acc * x_v + x_acc
            float nar = car * var - cai * vai;
            float nai = car * vai + cai * var;
            float nxr = car * vxr - cai * vxi + cxr;
            float nxi = car * vxi + cai * vxr + cxi;
            car = nar; cai = nai; cxr = nxr; cxi = nxi;
            if (f == 2u) break;
            --k;
        }

        // own inclusive = combine(prefix, own): a = a_own*a_pre, x = a_own*x_pre + x_own
        float iar = pr * car - pi * cai;
        float iai = pr * cai + pi * car;
        float ixr = pr * cxr - pi * cxi + yr;
        float ixi = pr * cxi + pi * cxr + yi;
        __hip_atomic_store(&vinc[vslot + 0], pack2f(iar, iai), __ATOMIC_RELAXED, __HIP_MEMORY_SCOPE_AGENT);
        __hip_atomic_store(&vinc[vslot + 1], pack2f(ixr, ixi), __ATOMIC_RELAXED, __HIP_MEMORY_SCOPE_AGENT);
        __syncthreads();
        if (threadIdx.x == 0)
            __hip_atomic_store(&flags[tile], 2u, __ATOMIC_RELEASE, __HIP_MEMORY_SCOPE_AGENT);

        sy_r = cxr; sy_i = cxi;
    }

    // ---- apply: recompute recurrence from seed, store [B,L,D,2] ----
    float fy_r = sy_r, fy_i = sy_i;
#pragma unroll
    for (int t = 0; t < T; ++t) {
        float a_r = lds[0 * TILE_FLOATS + t * DIM + d];
        float a_i = lds[1 * TILE_FLOATS + t * DIM + d];
        float x_r = lds[2 * TILE_FLOATS + t * DIM + d];
        float x_i = lds[3 * TILE_FLOATS + t * DIM + d];
        float t_r = a_r * fy_r - a_i * fy_i + x_r;
        float t_i = a_r * fy_i + a_i * fy_r + x_i;
        fy_r = t_r; fy_i = t_i;
        floatx2 o = {fy_r, fy_i};
        __builtin_nontemporal_store(o, (floatx2*)(outf + 2 * (tile_off + (size_t)t * DIM + d)));
    }
}

// ===========================================================================
// Fallback 3-kernel path (small workspace) — R10 forms, NT=64.
// ===========================================================================
template <int NT, int T>
__global__ __launch_bounds__(256) void k_tile_agg(
    const float* __restrict__ Ar, const float* __restrict__ Ai,
    const float* __restrict__ Xr, const float* __restrict__ Xi,
    float4* __restrict__ agg)
{
    int wave = threadIdx.x >> 6;
    int lane = threadIdx.x & 63;
    int tile = blockIdx.x * 4 + wave;
    int b = tile / NT;
    int j = tile - b * NT;
    int d = lane * 4;

    size_t base = ((size_t)b * SEQ + (size_t)j * T) * DIM + d;

    float pr[4], pi[4], yr[4], yi[4];
#pragma unroll
    for (int k = 0; k < 4; ++k) { pr[k] = 1.f; pi[k] = 0.f; yr[k] = 0.f; yi[k] = 0.f; }

#pragma unroll 4
    for (int t = 0; t < T; ++t) {
        size_t idx = base + (size_t)t * DIM;
        float4 a_re = *(const float4*)(Ar + idx);
        float4 a_im = *(const float4*)(Ai + idx);
        float4 x_re = *(const float4*)(Xr + idx);
        float4 x_im = *(const float4*)(Xi + idx);
        const float* par = (const float*)&a_re;
        const float* pai = (const float*)&a_im;
        const float* pxr = (const float*)&x_re;
        const float* pxi = (const float*)&x_im;
#pragma unroll
        for (int k = 0; k < 4; ++k) {
            float a_r = par[k], a_i = pai[k];
            float npr = a_r * pr[k] - a_i * pi[k];
            float npi = a_r * pi[k] + a_i * pr[k];
            pr[k] = npr; pi[k] = npi;
            float nyr = a_r * yr[k] - a_i * yi[k] + pxr[k];
            float nyi = a_r * yi[k] + a_i * yr[k] + pxi[k];
            yr[k] = nyr; yi[k] = nyi;
        }
    }

    size_t o = ((size_t)b * NT + j) * DIM + d;
#pragma unroll
    for (int k = 0; k < 4; ++k)
        agg[o + k] = make_float4(pr[k], pi[k], yr[k], yi[k]);
}

template <int NT>
__global__ __launch_bounds__(256) void k_scan_agg(float4* __restrict__ agg)
{
    constexpr int NTPL = NT / 64;
    int lane = threadIdx.x & 63;
    int col  = blockIdx.x * 4 + (threadIdx.x >> 6);
    int b = col >> 8;
    int d = col & 255;

    float4 v[NTPL];
    float lar = 1.f, lai = 0.f, lxr = 0.f, lxi = 0.f;
#pragma unroll
    for (int m = 0; m < NTPL; ++m) {
        v[m] = agg[((size_t)b * NT + lane * NTPL + m) * DIM + d];
        float nar = v[m].x * lar - v[m].y * lai;
        float nai = v[m].x * lai + v[m].y * lar;
        float nxr = v[m].x * lxr - v[m].y * lxi + v[m].z;
        float nxi = v[m].x * lxi + v[m].y * lxr + v[m].w;
        lar = nar; lai = nai; lxr = nxr; lxi = nxi;
    }

    float ar = lar, ai = lai, xr = lxr, xi = lxi;
#pragma unroll
    for (int off = 1; off < 64; off <<= 1) {
        float par = __shfl_up(ar, (unsigned)off, 64);
        float pai = __shfl_up(ai, (unsigned)off, 64);
        float pxr = __shfl_up(xr, (unsigned)off, 64);
        float pxi = __shfl_up(xi, (unsigned)off, 64);
        if (lane >= off) {
            float nar = ar * par - ai * pai;
            float nai = ar * pai + ai * par;
            float nxr = ar * pxr - ai * pxi + xr;
            float nxi = ar * pxi + ai * pxr + xi;
            ar = nar; ai = nai; xr = nxr; xi = nxi;
        }
    }

    float ear = __shfl_up(ar, 1u, 64);
    float eai = __shfl_up(ai, 1u, 64);
    float exr = __shfl_up(xr, 1u, 64);
    float exi = __shfl_up(xi, 1u, 64);
    if (lane == 0) { ear = 1.f; eai = 0.f; exr = 0.f; exi = 0.f; }

#pragma unroll
    for (int m = 0; m < NTPL; ++m) {
        agg[((size_t)b * NT + lane * NTPL + m) * DIM + d] =
            make_float4(exr, exi, 0.f, 0.f);
        float nar = v[m].x * ear - v[m].y * eai;
        float nai = v[m].x * eai + v[m].y * ear;
        float nxr = v[m].x * exr - v[m].y * exi + v[m].z;
        float nxi = v[m].x * exi + v[m].y * exr + v[m].w;
        ear = nar; eai = nai; exr = nxr; exi = nxi;
    }
}

template <int NT, int T>
__global__ __launch_bounds__(256, 8) void k_apply(
    const float* __restrict__ Ar, const float* __restrict__ Ai,
    const float* __restrict__ Xr, const float* __restrict__ Xi,
    const float4* __restrict__ agg, float* __restrict__ outf)
{
    int half = threadIdx.x >> 7;
    int wl   = threadIdx.x & 127;
    int tile = blockIdx.x * 2 + half;
    int b = tile / NT;
    int j = tile - b * NT;
    int d = wl * 2;

    float yr[2], yi[2];
    size_t o = ((size_t)b * NT + j) * DIM + d;
    {
        float4 p0 = agg[o];
        float4 p1 = agg[o + 1];
        yr[0] = p0.x; yi[0] = p0.y;
        yr[1] = p1.x; yi[1] = p1.y;
    }

    size_t base = ((size_t)b * SEQ + (size_t)j * T) * DIM + d;

#pragma unroll
    for (int t = 0; t < T; ++t) {
        size_t idx = base + (size_t)t * DIM;
        float2 a_re = *(const float2*)(Ar + idx);
        float2 a_im = *(const float2*)(Ai + idx);
        float2 x_re = *(const float2*)(Xr + idx);
        float2 x_im = *(const float2*)(Xi + idx);
        const float* par = (const float*)&a_re;
        const float* pai = (const float*)&a_im;
        const float* pxr = (const float*)&x_re;
        const float* pxi = (const float*)&x_im;
#pragma unroll
        for (int k = 0; k < 2; ++k) {
            float nyr = par[k] * yr[k] - pai[k] * yi[k] + pxr[k];
            float nyi = par[k] * yi[k] + pai[k] * yr[k] + pxi[k];
            yr[k] = nyr; yi[k] = nyi;
        }
        floatx4 o1 = (floatx4){yr[0], yi[0], yr[1], yi[1]};
        __builtin_nontemporal_store(o1, (floatx4*)(outf + 2 * idx));
    }
}

extern "C" void kernel_launch(void* const* d_in, const int* in_sizes, int n_in,
                              void* d_out, int out_size, void* d_ws, size_t ws_size,
                              hipStream_t stream)
{
    const float* Ar = (const float*)d_in[0];
    const float* Ai = (const float*)d_in[1];
    const float* Xr = (const float*)d_in[2];
    const float* Xi = (const float*)d_in[3];
    float* outf = (float*)d_out;

    if (ws_size >= WS_NEED) {
        char* ws = (char*)d_ws;
        unsigned* flags  = (unsigned*)ws;                       // 8 KB
        unsigned* ticket = (unsigned*)(ws + 8192);              // 4 B
        unsigned long long* vagg = (unsigned long long*)(ws + WS_HDR);
        unsigned long long* vinc = (unsigned long long*)(ws + WS_HDR + WS_VALS);

        // zero flags + ticket each launch (replay-safe, graph-capturable)
        hipMemsetAsync(d_ws, 0, WS_HDR, stream);

        k_scan_lookback<<<NTILES, 256, 0, stream>>>(
            Ar, Ai, Xr, Xi, outf, flags, ticket, vagg, vinc);
    } else {
        float4* agg = (float4*)d_ws;
        constexpr int NT = 64, T = SEQ / 64;
        dim3 block(256);
        dim3 grid1((BATCH * NT) / 4);
        dim3 grid3((BATCH * NT) / 2);
        k_tile_agg<NT, T><<<grid1, block, 0, stream>>>(Ar, Ai, Xr, Xi, agg);
        k_scan_agg<NT><<<(BATCH * DIM) / 4, block, 0, stream>>>(agg);
        k_apply<NT, T><<<grid3, block, 0, stream>>>(Ar, Ai, Xr, Xi, agg, outf);
    }
}

// Round 13
// 65.879 us; speedup vs baseline: 4.7752x; 4.7752x over previous
//
#include <hip/hip_runtime.h>

// Problem constants (from reference setup_inputs): B=8, L=4096, D=256, f32.
#define BATCH 8
#define SEQ   4096
#define DIM   256

typedef float floatx4 __attribute__((ext_vector_type(4)));

// ---------------------------------------------------------------------------
// R12 lesson: lookback frontier is serial (~360us). Back to 3-pass.
// R11 lesson: k1's time is HBM-traffic-INVARIANT (44us at 65MB or 8MB
// fetched) -> duty-cycle bound: __syncthreads drains vmcnt(0), so during
// compute/exit/relaunch no loads are outstanding. Fix (T3/T4 pattern):
// persistent blocks, double-buffered LDS subtiles, counted s_waitcnt vmcnt(8)
// + raw s_barrier -- next subtile's 8 global_load_lds stay in flight across
// the barrier; steady state never drains to 0.
//   subtile = 8 timesteps x 256 d x 4 arrays = 32KB. LDS = 2 x 32KB.
//   grid = 512 blocks (2/CU, exactly co-resident), 8 subtiles/block,
//   contiguous 256KB stream per block. agg tile (T=16) = 2 subtiles.
// ---------------------------------------------------------------------------
constexpr int NT_MAIN = 256;
constexpr int T_MAIN  = SEQ / NT_MAIN;      // 16
constexpr int TSUB    = 8;                  // timesteps per staged subtile
constexpr int SUB_FLOATS = TSUB * DIM;      // 2048 floats = 8KB per array
constexpr int NSUB_BLK   = 8;               // subtiles per block
constexpr int NSUB_TOT   = BATCH * SEQ / TSUB;   // 4096

__global__ __launch_bounds__(256, 2) void k_tile_agg_pipe(
    const float* __restrict__ Ar, const float* __restrict__ Ai,
    const float* __restrict__ Xr, const float* __restrict__ Xi,
    float4* __restrict__ agg)
{
    __shared__ float lds[2][4][SUB_FLOATS];           // 64 KB

    int wave = threadIdx.x >> 6, lane = threadIdx.x & 63;
    int d = threadIdx.x;
    const float* src = (wave == 0) ? Ar : (wave == 1) ? Ai
                      : (wave == 2) ? Xr : Xi;

    int s0 = blockIdx.x * NSUB_BLK;                   // first global subtile
    // linear float offset of subtile s is exactly s * SUB_FLOATS
    const float* gsrc = src + (size_t)s0 * SUB_FLOATS + (size_t)lane * 4;

    auto ISSUE = [&](int i) {                         // stage subtile s0+i
        const float* g = gsrc + (size_t)i * SUB_FLOATS;
        float* l = &lds[i & 1][wave][0];              // wave-uniform dest
#pragma unroll
        for (int r = 0; r < TSUB; ++r) {
            __builtin_amdgcn_global_load_lds(
                (const __attribute__((address_space(1))) void*)(g + r * DIM),
                (__attribute__((address_space(3))) void*)(l + r * DIM),
                16, 0, 0);
        }
    };

    float pr = 1.f, pi = 0.f, yr = 0.f, yi = 0.f;

    ISSUE(0);
#pragma unroll 1
    for (int i = 0; i < NSUB_BLK; ++i) {
        if (i + 1 < NSUB_BLK) {
            ISSUE(i + 1);                              // keep 8 loads in flight
            asm volatile("s_waitcnt vmcnt(8)" ::: "memory");   // subtile i done
        } else {
            asm volatile("s_waitcnt vmcnt(0)" ::: "memory");
        }
        __builtin_amdgcn_s_barrier();                  // all 4 arrays present
        __builtin_amdgcn_sched_barrier(0);             // no hoisting past wait

        const int buf = i & 1;
#pragma unroll
        for (int t = 0; t < TSUB; ++t) {
            float a_r = lds[buf][0][t * DIM + d];
            float a_i = lds[buf][1][t * DIM + d];
            float x_r = lds[buf][2][t * DIM + d];
            float x_i = lds[buf][3][t * DIM + d];
            float npr = a_r * pr - a_i * pi;
            float npi = a_r * pi + a_i * pr;
            pr = npr; pi = npi;
            float nyr = a_r * yr - a_i * yi + x_r;
            float nyi = a_r * yi + a_i * yr + x_i;
            yr = nyr; yi = nyi;
        }
        if (i & 1) {                                   // finished an agg tile
            int s = s0 + i;                            // global subtile (odd)
            agg[(size_t)(s >> 1) * DIM + d] = make_float4(pr, pi, yr, yi);
            pr = 1.f; pi = 0.f; yr = 0.f; yi = 0.f;
        }
        __builtin_amdgcn_s_barrier();                  // reads done before next
    }
}

// ---------------------------------------------------------------------------
// Kernel 2 (R8 form): wave-parallel exclusive scan of tile aggregates.
// One wave per (b,d) column; lane owns NTPL = NT/64 consecutive tiles.
// ---------------------------------------------------------------------------
template <int NT>
__global__ __launch_bounds__(256) void k_scan_agg(float4* __restrict__ agg)
{
    constexpr int NTPL = NT / 64;
    int lane = threadIdx.x & 63;
    int col  = blockIdx.x * 4 + (threadIdx.x >> 6);   // in [0, BATCH*DIM)
    int b = col >> 8;
    int d = col & 255;

    float4 v[NTPL];
    float lar = 1.f, lai = 0.f, lxr = 0.f, lxi = 0.f;
#pragma unroll
    for (int m = 0; m < NTPL; ++m) {
        v[m] = agg[((size_t)b * NT + lane * NTPL + m) * DIM + d];
        float nar = v[m].x * lar - v[m].y * lai;
        float nai = v[m].x * lai + v[m].y * lar;
        float nxr = v[m].x * lxr - v[m].y * lxi + v[m].z;
        float nxi = v[m].x * lxi + v[m].y * lxr + v[m].w;
        lar = nar; lai = nai; lxr = nxr; lxi = nxi;
    }

    float ar = lar, ai = lai, xr = lxr, xi = lxi;
#pragma unroll
    for (int off = 1; off < 64; off <<= 1) {
        float par = __shfl_up(ar, (unsigned)off, 64);
        float pai = __shfl_up(ai, (unsigned)off, 64);
        float pxr = __shfl_up(xr, (unsigned)off, 64);
        float pxi = __shfl_up(xi, (unsigned)off, 64);
        if (lane >= off) {
            float nar = ar * par - ai * pai;
            float nai = ar * pai + ai * par;
            float nxr = ar * pxr - ai * pxi + xr;
            float nxi = ar * pxi + ai * pxr + xi;
            ar = nar; ai = nai; xr = nxr; xi = nxi;
        }
    }

    float ear = __shfl_up(ar, 1u, 64);
    float eai = __shfl_up(ai, 1u, 64);
    float exr = __shfl_up(xr, 1u, 64);
    float exi = __shfl_up(xi, 1u, 64);
    if (lane == 0) { ear = 1.f; eai = 0.f; exr = 0.f; exi = 0.f; }

#pragma unroll
    for (int m = 0; m < NTPL; ++m) {
        agg[((size_t)b * NT + lane * NTPL + m) * DIM + d] =
            make_float4(exr, exi, 0.f, 0.f);
        float nar = v[m].x * ear - v[m].y * eai;
        float nai = v[m].x * eai + v[m].y * ear;
        float nxr = v[m].x * exr - v[m].y * exi + v[m].z;
        float nxi = v[m].x * exi + v[m].y * exr + v[m].w;
        ear = nar; eai = nai; exr = nxr; exi = nxi;
    }
}

// ---------------------------------------------------------------------------
// Kernel 3 (R8 fast form, unchanged): seed y from tile prefix, recompute
// recurrence, write out. Tile = 2 waves; 2 cols/lane (float2 loads); one
// contiguous 16B nontemporal store per lane per t ([B,L,D,2] layout).
// ---------------------------------------------------------------------------
template <int NT, int T>
__global__ __launch_bounds__(256, 8) void k_apply(
    const float* __restrict__ Ar, const float* __restrict__ Ai,
    const float* __restrict__ Xr, const float* __restrict__ Xi,
    const float4* __restrict__ agg, float* __restrict__ outf)
{
    int half = threadIdx.x >> 7;
    int wl   = threadIdx.x & 127;
    int tile = blockIdx.x * 2 + half;
    int b = tile / NT;
    int j = tile - b * NT;
    int d = wl * 2;

    float yr[2], yi[2];
    size_t o = ((size_t)b * NT + j) * DIM + d;
    {
        float4 p0 = agg[o];
        float4 p1 = agg[o + 1];
        yr[0] = p0.x; yi[0] = p0.y;
        yr[1] = p1.x; yi[1] = p1.y;
    }

    size_t base = ((size_t)b * SEQ + (size_t)j * T) * DIM + d;

#pragma unroll
    for (int t = 0; t < T; ++t) {
        size_t idx = base + (size_t)t * DIM;
        float2 a_re = *(const float2*)(Ar + idx);
        float2 a_im = *(const float2*)(Ai + idx);
        float2 x_re = *(const float2*)(Xr + idx);
        float2 x_im = *(const float2*)(Xi + idx);
        const float* par = (const float*)&a_re;
        const float* pai = (const float*)&a_im;
        const float* pxr = (const float*)&x_re;
        const float* pxi = (const float*)&x_im;
#pragma unroll
        for (int k = 0; k < 2; ++k) {
            float nyr = par[k] * yr[k] - pai[k] * yi[k] + pxr[k];
            float nyi = par[k] * yi[k] + pai[k] * yr[k] + pxi[k];
            yr[k] = nyr; yi[k] = nyi;
        }
        floatx4 o1 = (floatx4){yr[0], yi[0], yr[1], yi[1]};
        __builtin_nontemporal_store(o1, (floatx4*)(outf + 2 * idx));
    }
}

// ===========================================================================
// Fallback 3-kernel path (small workspace) — R10 forms, NT=64.
// ===========================================================================
template <int NT, int T>
__global__ __launch_bounds__(256) void k_tile_agg(
    const float* __restrict__ Ar, const float* __restrict__ Ai,
    const float* __restrict__ Xr, const float* __restrict__ Xi,
    float4* __restrict__ agg)
{
    int wave = threadIdx.x >> 6;
    int lane = threadIdx.x & 63;
    int tile = blockIdx.x * 4 + wave;
    int b = tile / NT;
    int j = tile - b * NT;
    int d = lane * 4;

    size_t base = ((size_t)b * SEQ + (size_t)j * T) * DIM + d;

    float pr[4], pi[4], yr[4], yi[4];
#pragma unroll
    for (int k = 0; k < 4; ++k) { pr[k] = 1.f; pi[k] = 0.f; yr[k] = 0.f; yi[k] = 0.f; }

#pragma unroll 4
    for (int t = 0; t < T; ++t) {
        size_t idx = base + (size_t)t * DIM;
        float4 a_re = *(const float4*)(Ar + idx);
        float4 a_im = *(const float4*)(Ai + idx);
        float4 x_re = *(const float4*)(Xr + idx);
        float4 x_im = *(const float4*)(Xi + idx);
        const float* par = (const float*)&a_re;
        const float* pai = (const float*)&a_im;
        const float* pxr = (const float*)&x_re;
        const float* pxi = (const float*)&x_im;
#pragma unroll
        for (int k = 0; k < 4; ++k) {
            float a_r = par[k], a_i = pai[k];
            float npr = a_r * pr[k] - a_i * pi[k];
            float npi = a_r * pi[k] + a_i * pr[k];
            pr[k] = npr; pi[k] = npi;
            float nyr = a_r * yr[k] - a_i * yi[k] + pxr[k];
            float nyi = a_r * yi[k] + a_i * yr[k] + pxi[k];
            yr[k] = nyr; yi[k] = nyi;
        }
    }

    size_t o = ((size_t)b * NT + j) * DIM + d;
#pragma unroll
    for (int k = 0; k < 4; ++k)
        agg[o + k] = make_float4(pr[k], pi[k], yr[k], yi[k]);
}

extern "C" void kernel_launch(void* const* d_in, const int* in_sizes, int n_in,
                              void* d_out, int out_size, void* d_ws, size_t ws_size,
                              hipStream_t stream)
{
    const float* Ar = (const float*)d_in[0];
    const float* Ai = (const float*)d_in[1];
    const float* Xr = (const float*)d_in[2];
    const float* Xi = (const float*)d_in[3];
    float* outf = (float*)d_out;
    float4* agg = (float4*)d_ws;

    dim3 block(256);

    if (ws_size >= (size_t)BATCH * NT_MAIN * DIM * sizeof(float4)) {
        constexpr int NT = NT_MAIN, T = T_MAIN;        // 256 / 16
        dim3 gridP(NSUB_TOT / NSUB_BLK);               // 512 blocks, 2/CU
        dim3 grid3((BATCH * NT) / 2);                  // k3: 2 waves/tile
        k_tile_agg_pipe<<<gridP, block, 0, stream>>>(Ar, Ai, Xr, Xi, agg);
        k_scan_agg<NT><<<(BATCH * DIM) / 4, block, 0, stream>>>(agg);
        k_apply<NT, T><<<grid3, block, 0, stream>>>(Ar, Ai, Xr, Xi, agg, outf);
    } else {
        constexpr int NT = 64, T = SEQ / 64;
        dim3 grid1((BATCH * NT) / 4);
        dim3 grid3((BATCH * NT) / 2);
        k_tile_agg<NT, T><<<grid1, block, 0, stream>>>(Ar, Ai, Xr, Xi, agg);
        k_scan_agg<NT><<<(BATCH * DIM) / 4, block, 0, stream>>>(agg);
        k_apply<NT, T><<<grid3, block, 0, stream>>>(Ar, Ai, Xr, Xi, agg, outf);
    }
}

// Round 14
// 63.585 us; speedup vs baseline: 4.9474x; 1.0361x over previous
//
#include <hip/hip_runtime.h>

// Problem constants (from reference setup_inputs): B=8, L=4096, D=256, f32.
#define BATCH 8
#define SEQ   4096
#define DIM   256

typedef float floatx4 __attribute__((ext_vector_type(4)));

// R14: k1/k2 structure = R13 verbatim (best total 65.9us). Changes:
//  - k3 stores: nontemporal -> PLAIN (R9 showed WRITE_SIZE=120MB for 67MB
//    output with nt -> testing nt write amplification).
//  - k2 writes compact float2 seed array; k3 reads 8B/col seed (was 16B).
// Model: both streaming passes sit at ~4.5-5 TB/s effective; pipeline is
// near the two-input-pass floor (~55-61us). This round trims write traffic.

constexpr int NT_MAIN = 256;
constexpr int T_MAIN  = SEQ / NT_MAIN;      // 16
constexpr int TSUB    = 8;                  // timesteps per staged subtile
constexpr int SUB_FLOATS = TSUB * DIM;      // 2048 floats = 8KB per array
constexpr int NSUB_BLK   = 8;               // subtiles per block
constexpr int NSUB_TOT   = BATCH * SEQ / TSUB;   // 4096

constexpr size_t AGG_BYTES  = (size_t)BATCH * NT_MAIN * DIM * 16;   // 16.8 MB
constexpr size_t SEED_BYTES = (size_t)BATCH * NT_MAIN * DIM * 8;    //  8.4 MB

// ---------------------------------------------------------------------------
// Kernel 1 (R13 form, unchanged): persistent pipelined tile aggregates.
// ---------------------------------------------------------------------------
__global__ __launch_bounds__(256, 2) void k_tile_agg_pipe(
    const float* __restrict__ Ar, const float* __restrict__ Ai,
    const float* __restrict__ Xr, const float* __restrict__ Xi,
    float4* __restrict__ agg)
{
    __shared__ float lds[2][4][SUB_FLOATS];           // 64 KB

    int wave = threadIdx.x >> 6, lane = threadIdx.x & 63;
    int d = threadIdx.x;
    const float* src = (wave == 0) ? Ar : (wave == 1) ? Ai
                      : (wave == 2) ? Xr : Xi;

    int s0 = blockIdx.x * NSUB_BLK;                   // first global subtile
    const float* gsrc = src + (size_t)s0 * SUB_FLOATS + (size_t)lane * 4;

    auto ISSUE = [&](int i) {
        const float* g = gsrc + (size_t)i * SUB_FLOATS;
        float* l = &lds[i & 1][wave][0];
#pragma unroll
        for (int r = 0; r < TSUB; ++r) {
            __builtin_amdgcn_global_load_lds(
                (const __attribute__((address_space(1))) void*)(g + r * DIM),
                (__attribute__((address_space(3))) void*)(l + r * DIM),
                16, 0, 0);
        }
    };

    float pr = 1.f, pi = 0.f, yr = 0.f, yi = 0.f;

    ISSUE(0);
#pragma unroll 1
    for (int i = 0; i < NSUB_BLK; ++i) {
        if (i + 1 < NSUB_BLK) {
            ISSUE(i + 1);
            asm volatile("s_waitcnt vmcnt(8)" ::: "memory");
        } else {
            asm volatile("s_waitcnt vmcnt(0)" ::: "memory");
        }
        __builtin_amdgcn_s_barrier();
        __builtin_amdgcn_sched_barrier(0);

        const int buf = i & 1;
#pragma unroll
        for (int t = 0; t < TSUB; ++t) {
            float a_r = lds[buf][0][t * DIM + d];
            float a_i = lds[buf][1][t * DIM + d];
            float x_r = lds[buf][2][t * DIM + d];
            float x_i = lds[buf][3][t * DIM + d];
            float npr = a_r * pr - a_i * pi;
            float npi = a_r * pi + a_i * pr;
            pr = npr; pi = npi;
            float nyr = a_r * yr - a_i * yi + x_r;
            float nyi = a_r * yi + a_i * yr + x_i;
            yr = nyr; yi = nyi;
        }
        if (i & 1) {
            int s = s0 + i;
            agg[(size_t)(s >> 1) * DIM + d] = make_float4(pr, pi, yr, yi);
            pr = 1.f; pi = 0.f; yr = 0.f; yi = 0.f;
        }
        __builtin_amdgcn_s_barrier();
    }
}

// ---------------------------------------------------------------------------
// Kernel 2: wave-parallel exclusive scan of tile aggregates; NOW also emits
// a compact float2 seed (incoming y) per (tile, d) for k3.
// ---------------------------------------------------------------------------
template <int NT>
__global__ __launch_bounds__(256) void k_scan_agg(
    float4* __restrict__ agg, float2* __restrict__ seed)
{
    constexpr int NTPL = NT / 64;
    int lane = threadIdx.x & 63;
    int col  = blockIdx.x * 4 + (threadIdx.x >> 6);   // in [0, BATCH*DIM)
    int b = col >> 8;
    int d = col & 255;

    float4 v[NTPL];
    float lar = 1.f, lai = 0.f, lxr = 0.f, lxi = 0.f;
#pragma unroll
    for (int m = 0; m < NTPL; ++m) {
        v[m] = agg[((size_t)b * NT + lane * NTPL + m) * DIM + d];
        float nar = v[m].x * lar - v[m].y * lai;
        float nai = v[m].x * lai + v[m].y * lar;
        float nxr = v[m].x * lxr - v[m].y * lxi + v[m].z;
        float nxi = v[m].x * lxi + v[m].y * lxr + v[m].w;
        lar = nar; lai = nai; lxr = nxr; lxi = nxi;
    }

    float ar = lar, ai = lai, xr = lxr, xi = lxi;
#pragma unroll
    for (int off = 1; off < 64; off <<= 1) {
        float par = __shfl_up(ar, (unsigned)off, 64);
        float pai = __shfl_up(ai, (unsigned)off, 64);
        float pxr = __shfl_up(xr, (unsigned)off, 64);
        float pxi = __shfl_up(xi, (unsigned)off, 64);
        if (lane >= off) {
            float nar = ar * par - ai * pai;
            float nai = ar * pai + ai * par;
            float nxr = ar * pxr - ai * pxi + xr;
            float nxi = ar * pxi + ai * pxr + xi;
            ar = nar; ai = nai; xr = nxr; xi = nxi;
        }
    }

    float ear = __shfl_up(ar, 1u, 64);
    float eai = __shfl_up(ai, 1u, 64);
    float exr = __shfl_up(xr, 1u, 64);
    float exi = __shfl_up(xi, 1u, 64);
    if (lane == 0) { ear = 1.f; eai = 0.f; exr = 0.f; exi = 0.f; }

#pragma unroll
    for (int m = 0; m < NTPL; ++m) {
        seed[((size_t)b * NT + lane * NTPL + m) * DIM + d] =
            make_float2(exr, exi);
        float nar = v[m].x * ear - v[m].y * eai;
        float nai = v[m].x * eai + v[m].y * ear;
        float nxr = v[m].x * exr - v[m].y * exi + v[m].z;
        float nxi = v[m].x * exi + v[m].y * exr + v[m].w;
        ear = nar; eai = nai; exr = nxr; exi = nxi;
    }
}

// ---------------------------------------------------------------------------
// Kernel 3: seed from compact float2, recompute recurrence, PLAIN float4
// stores (nt hint removed — testing R9's 1.8x write amplification).
// Tile = 2 waves; 2 cols/lane (float2 loads); 16B store per lane per t.
// ---------------------------------------------------------------------------
template <int NT, int T>
__global__ __launch_bounds__(256, 8) void k_apply(
    const float* __restrict__ Ar, const float* __restrict__ Ai,
    const float* __restrict__ Xr, const float* __restrict__ Xi,
    const float2* __restrict__ seed, float* __restrict__ outf)
{
    int half = threadIdx.x >> 7;
    int wl   = threadIdx.x & 127;
    int tile = blockIdx.x * 2 + half;
    int b = tile / NT;
    int j = tile - b * NT;
    int d = wl * 2;

    float yr[2], yi[2];
    size_t o = ((size_t)b * NT + j) * DIM + d;
    {
        float2 s0 = seed[o];
        float2 s1 = seed[o + 1];
        yr[0] = s0.x; yi[0] = s0.y;
        yr[1] = s1.x; yi[1] = s1.y;
    }

    size_t base = ((size_t)b * SEQ + (size_t)j * T) * DIM + d;

#pragma unroll
    for (int t = 0; t < T; ++t) {
        size_t idx = base + (size_t)t * DIM;
        float2 a_re = *(const float2*)(Ar + idx);
        float2 a_im = *(const float2*)(Ai + idx);
        float2 x_re = *(const float2*)(Xr + idx);
        float2 x_im = *(const float2*)(Xi + idx);
        const float* par = (const float*)&a_re;
        const float* pai = (const float*)&a_im;
        const float* pxr = (const float*)&x_re;
        const float* pxi = (const float*)&x_im;
#pragma unroll
        for (int k = 0; k < 2; ++k) {
            float nyr = par[k] * yr[k] - pai[k] * yi[k] + pxr[k];
            float nyi = par[k] * yi[k] + pai[k] * yr[k] + pxi[k];
            yr[k] = nyr; yi[k] = nyi;
        }
        *(float4*)(outf + 2 * idx) = make_float4(yr[0], yi[0], yr[1], yi[1]);
    }
}

// ===========================================================================
// Fallback 3-kernel path (small workspace) — NT=64, self-contained.
// ===========================================================================
template <int NT, int T>
__global__ __launch_bounds__(256) void k_tile_agg_fb(
    const float* __restrict__ Ar, const float* __restrict__ Ai,
    const float* __restrict__ Xr, const float* __restrict__ Xi,
    float4* __restrict__ agg)
{
    int wave = threadIdx.x >> 6;
    int lane = threadIdx.x & 63;
    int tile = blockIdx.x * 4 + wave;
    int b = tile / NT;
    int j = tile - b * NT;
    int d = lane * 4;

    size_t base = ((size_t)b * SEQ + (size_t)j * T) * DIM + d;

    float pr[4], pi[4], yr[4], yi[4];
#pragma unroll
    for (int k = 0; k < 4; ++k) { pr[k] = 1.f; pi[k] = 0.f; yr[k] = 0.f; yi[k] = 0.f; }

#pragma unroll 4
    for (int t = 0; t < T; ++t) {
        size_t idx = base + (size_t)t * DIM;
        float4 a_re = *(const float4*)(Ar + idx);
        float4 a_im = *(const float4*)(Ai + idx);
        float4 x_re = *(const float4*)(Xr + idx);
        float4 x_im = *(const float4*)(Xi + idx);
        const float* par = (const float*)&a_re;
        const float* pai = (const float*)&a_im;
        const float* pxr = (const float*)&x_re;
        const float* pxi = (const float*)&x_im;
#pragma unroll
        for (int k = 0; k < 4; ++k) {
            float a_r = par[k], a_i = pai[k];
            float npr = a_r * pr[k] - a_i * pi[k];
            float npi = a_r * pi[k] + a_i * pr[k];
            pr[k] = npr; pi[k] = npi;
            float nyr = a_r * yr[k] - a_i * yi[k] + pxr[k];
            float nyi = a_r * yi[k] + a_i * yr[k] + pxi[k];
            yr[k] = nyr; yi[k] = nyi;
        }
    }

    size_t o = ((size_t)b * NT + j) * DIM + d;
#pragma unroll
    for (int k = 0; k < 4; ++k)
        agg[o + k] = make_float4(pr[k], pi[k], yr[k], yi[k]);
}

template <int NT, int T>
__global__ __launch_bounds__(256, 8) void k_apply_fb(
    const float* __restrict__ Ar, const float* __restrict__ Ai,
    const float* __restrict__ Xr, const float* __restrict__ Xi,
    const float4* __restrict__ agg, float* __restrict__ outf)
{
    int half = threadIdx.x >> 7;
    int wl   = threadIdx.x & 127;
    int tile = blockIdx.x * 2 + half;
    int b = tile / NT;
    int j = tile - b * NT;
    int d = wl * 2;

    float yr[2], yi[2];
    size_t o = ((size_t)b * NT + j) * DIM + d;
    {
        float4 p0 = agg[o];
        float4 p1 = agg[o + 1];
        yr[0] = p0.x; yi[0] = p0.y;
        yr[1] = p1.x; yi[1] = p1.y;
    }

    size_t base = ((size_t)b * SEQ + (size_t)j * T) * DIM + d;

#pragma unroll
    for (int t = 0; t < T; ++t) {
        size_t idx = base + (size_t)t * DIM;
        float2 a_re = *(const float2*)(Ar + idx);
        float2 a_im = *(const float2*)(Ai + idx);
        float2 x_re = *(const float2*)(Xr + idx);
        float2 x_im = *(const float2*)(Xi + idx);
        const float* par = (const float*)&a_re;
        const float* pai = (const float*)&a_im;
        const float* pxr = (const float*)&x_re;
        const float* pxi = (const float*)&x_im;
#pragma unroll
        for (int k = 0; k < 2; ++k) {
            float nyr = par[k] * yr[k] - pai[k] * yi[k] + pxr[k];
            float nyi = par[k] * yi[k] + pai[k] * yr[k] + pxi[k];
            yr[k] = nyr; yi[k] = nyi;
        }
        *(float4*)(outf + 2 * idx) = make_float4(yr[0], yi[0], yr[1], yi[1]);
    }
}

// Fallback k2: scan in place, seeds stored back into agg (x,y fields).
template <int NT>
__global__ __launch_bounds__(256) void k_scan_agg_fb(float4* __restrict__ agg)
{
    constexpr int NTPL = NT / 64;
    int lane = threadIdx.x & 63;
    int col  = blockIdx.x * 4 + (threadIdx.x >> 6);
    int b = col >> 8;
    int d = col & 255;

    float4 v[NTPL];
    float lar = 1.f, lai = 0.f, lxr = 0.f, lxi = 0.f;
#pragma unroll
    for (int m = 0; m < NTPL; ++m) {
        v[m] = agg[((size_t)b * NT + lane * NTPL + m) * DIM + d];
        float nar = v[m].x * lar - v[m].y * lai;
        float nai = v[m].x * lai + v[m].y * lar;
        float nxr = v[m].x * lxr - v[m].y * lxi + v[m].z;
        float nxi = v[m].x * lxi + v[m].y * lxr + v[m].w;
        lar = nar; lai = nai; lxr = nxr; lxi = nxi;
    }

    float ar = lar, ai = lai, xr = lxr, xi = lxi;
#pragma unroll
    for (int off = 1; off < 64; off <<= 1) {
        float par = __shfl_up(ar, (unsigned)off, 64);
        float pai = __shfl_up(ai, (unsigned)off, 64);
        float pxr = __shfl_up(xr, (unsigned)off, 64);
        float pxi = __shfl_up(xi, (unsigned)off, 64);
        if (lane >= off) {
            float nar = ar * par - ai * pai;
            float nai = ar * pai + ai * par;
            float nxr = ar * pxr - ai * pxi + xr;
            float nxi = ar * pxi + ai * pxr + xi;
            ar = nar; ai = nai; xr = nxr; xi = nxi;
        }
    }

    float ear = __shfl_up(ar, 1u, 64);
    float eai = __shfl_up(ai, 1u, 64);
    float exr = __shfl_up(xr, 1u, 64);
    float exi = __shfl_up(xi, 1u, 64);
    if (lane == 0) { ear = 1.f; eai = 0.f; exr = 0.f; exi = 0.f; }

#pragma unroll
    for (int m = 0; m < NTPL; ++m) {
        agg[((size_t)b * NT + lane * NTPL + m) * DIM + d] =
            make_float4(exr, exi, 0.f, 0.f);
        float nar = v[m].x * ear - v[m].y * eai;
        float nai = v[m].x * eai + v[m].y * ear;
        float nxr = v[m].x * exr - v[m].y * exi + v[m].z;
        float nxi = v[m].x * exi + v[m].y * exr + v[m].w;
        ear = nar; eai = nai; exr = nxr; exi = nxi;
    }
}

extern "C" void kernel_launch(void* const* d_in, const int* in_sizes, int n_in,
                              void* d_out, int out_size, void* d_ws, size_t ws_size,
                              hipStream_t stream)
{
    const float* Ar = (const float*)d_in[0];
    const float* Ai = (const float*)d_in[1];
    const float* Xr = (const float*)d_in[2];
    const float* Xi = (const float*)d_in[3];
    float* outf = (float*)d_out;

    dim3 block(256);

    if (ws_size >= AGG_BYTES + SEED_BYTES) {
        constexpr int NT = NT_MAIN, T = T_MAIN;        // 256 / 16
        float4* agg  = (float4*)d_ws;
        float2* seed = (float2*)((char*)d_ws + AGG_BYTES);
        dim3 gridP(NSUB_TOT / NSUB_BLK);               // 512 blocks, 2/CU
        dim3 grid3((BATCH * NT) / 2);                  // k3: 2 waves/tile
        k_tile_agg_pipe<<<gridP, block, 0, stream>>>(Ar, Ai, Xr, Xi, agg);
        k_scan_agg<NT><<<(BATCH * DIM) / 4, block, 0, stream>>>(agg, seed);
        k_apply<NT, T><<<grid3, block, 0, stream>>>(Ar, Ai, Xr, Xi, seed, outf);
    } else {
        constexpr int NT = 64, T = SEQ / 64;
        float4* agg = (float4*)d_ws;
        dim3 grid1((BATCH * NT) / 4);
        dim3 grid3((BATCH * NT) / 2);
        k_tile_agg_fb<NT, T><<<grid1, block, 0, stream>>>(Ar, Ai, Xr, Xi, agg);
        k_scan_agg_fb<NT><<<(BATCH * DIM) / 4, block, 0, stream>>>(agg);
        k_apply_fb<NT, T><<<grid3, block, 0, stream>>>(Ar, Ai, Xr, Xi, agg, outf);
    }
}

// Round 15
// 63.198 us; speedup vs baseline: 4.9777x; 1.0061x over previous
//
#include <hip/hip_runtime.h>

// Problem constants (from reference setup_inputs): B=8, L=4096, D=256, f32.
#define BATCH 8
#define SEQ   4096
#define DIM   256

typedef float floatx4 __attribute__((ext_vector_type(4)));

// R15: single variable vs R14 — k1_pipe occupancy 2 -> 4 blocks/CU.
// Cross-round invariant: ~1.4 load-insts/us/wave regardless of load kind;
// per-CU read rate ~4.6 B/cy at 8 staging waves/CU. Test: 16 staging
// waves/CU (TSUB=4, LDS 32KB dbuf, grid 1024, launch_bounds(256,4),
// counted vmcnt(4)). If k1 is unchanged, the per-CU read wall is
// structure-independent -> declare roofline.

constexpr int NT_MAIN = 256;
constexpr int T_MAIN  = SEQ / NT_MAIN;      // 16
constexpr int TSUB    = 4;                  // timesteps per staged subtile
constexpr int SUB_FLOATS = TSUB * DIM;      // 1024 floats = 4KB per array
constexpr int NSUB_BLK   = 8;               // subtiles per block (32 steps)
constexpr int NSUB_TOT   = BATCH * SEQ / TSUB;   // 8192
constexpr int SUB_PER_TILE = T_MAIN / TSUB; // 4 subtiles per agg tile

constexpr size_t AGG_BYTES  = (size_t)BATCH * NT_MAIN * DIM * 16;   // 16.8 MB
constexpr size_t SEED_BYTES = (size_t)BATCH * NT_MAIN * DIM * 8;    //  8.4 MB

// ---------------------------------------------------------------------------
// Kernel 1: persistent pipelined tile aggregates, 4 blocks/CU.
// ---------------------------------------------------------------------------
__global__ __launch_bounds__(256, 4) void k_tile_agg_pipe(
    const float* __restrict__ Ar, const float* __restrict__ Ai,
    const float* __restrict__ Xr, const float* __restrict__ Xi,
    float4* __restrict__ agg)
{
    __shared__ float lds[2][4][SUB_FLOATS];           // 32 KB

    int wave = threadIdx.x >> 6, lane = threadIdx.x & 63;
    int d = threadIdx.x;
    const float* src = (wave == 0) ? Ar : (wave == 1) ? Ai
                      : (wave == 2) ? Xr : Xi;

    int s0 = blockIdx.x * NSUB_BLK;                   // first global subtile
    const float* gsrc = src + (size_t)s0 * SUB_FLOATS + (size_t)lane * 4;

    auto ISSUE = [&](int i) {                         // stage subtile s0+i
        const float* g = gsrc + (size_t)i * SUB_FLOATS;
        float* l = &lds[i & 1][wave][0];              // wave-uniform dest
#pragma unroll
        for (int r = 0; r < TSUB; ++r) {
            __builtin_amdgcn_global_load_lds(
                (const __attribute__((address_space(1))) void*)(g + r * DIM),
                (__attribute__((address_space(3))) void*)(l + r * DIM),
                16, 0, 0);
        }
    };

    float pr = 1.f, pi = 0.f, yr = 0.f, yi = 0.f;

    ISSUE(0);
#pragma unroll 1
    for (int i = 0; i < NSUB_BLK; ++i) {
        if (i + 1 < NSUB_BLK) {
            ISSUE(i + 1);                              // keep next subtile in flight
            asm volatile("s_waitcnt vmcnt(4)" ::: "memory");   // subtile i done
        } else {
            asm volatile("s_waitcnt vmcnt(0)" ::: "memory");
        }
        __builtin_amdgcn_s_barrier();                  // all 4 arrays present
        __builtin_amdgcn_sched_barrier(0);

        const int buf = i & 1;
#pragma unroll
        for (int t = 0; t < TSUB; ++t) {
            float a_r = lds[buf][0][t * DIM + d];
            float a_i = lds[buf][1][t * DIM + d];
            float x_r = lds[buf][2][t * DIM + d];
            float x_i = lds[buf][3][t * DIM + d];
            float npr = a_r * pr - a_i * pi;
            float npi = a_r * pi + a_i * pr;
            pr = npr; pi = npi;
            float nyr = a_r * yr - a_i * yi + x_r;
            float nyi = a_r * yi + a_i * yr + x_i;
            yr = nyr; yi = nyi;
        }
        if ((i & (SUB_PER_TILE - 1)) == SUB_PER_TILE - 1) {   // tile finished
            int s = s0 + i;
            agg[(size_t)(s / SUB_PER_TILE) * DIM + d] = make_float4(pr, pi, yr, yi);
            pr = 1.f; pi = 0.f; yr = 0.f; yi = 0.f;
        }
        __builtin_amdgcn_s_barrier();                  // reads done before overwrite
    }
}

// ---------------------------------------------------------------------------
// Kernel 2 (R14 form): wave-parallel exclusive scan; emits float2 seed.
// ---------------------------------------------------------------------------
template <int NT>
__global__ __launch_bounds__(256) void k_scan_agg(
    float4* __restrict__ agg, float2* __restrict__ seed)
{
    constexpr int NTPL = NT / 64;
    int lane = threadIdx.x & 63;
    int col  = blockIdx.x * 4 + (threadIdx.x >> 6);   // in [0, BATCH*DIM)
    int b = col >> 8;
    int d = col & 255;

    float4 v[NTPL];
    float lar = 1.f, lai = 0.f, lxr = 0.f, lxi = 0.f;
#pragma unroll
    for (int m = 0; m < NTPL; ++m) {
        v[m] = agg[((size_t)b * NT + lane * NTPL + m) * DIM + d];
        float nar = v[m].x * lar - v[m].y * lai;
        float nai = v[m].x * lai + v[m].y * lar;
        float nxr = v[m].x * lxr - v[m].y * lxi + v[m].z;
        float nxi = v[m].x * lxi + v[m].y * lxr + v[m].w;
        lar = nar; lai = nai; lxr = nxr; lxi = nxi;
    }

    float ar = lar, ai = lai, xr = lxr, xi = lxi;
#pragma unroll
    for (int off = 1; off < 64; off <<= 1) {
        float par = __shfl_up(ar, (unsigned)off, 64);
        float pai = __shfl_up(ai, (unsigned)off, 64);
        float pxr = __shfl_up(xr, (unsigned)off, 64);
        float pxi = __shfl_up(xi, (unsigned)off, 64);
        if (lane >= off) {
            float nar = ar * par - ai * pai;
            float nai = ar * pai + ai * par;
            float nxr = ar * pxr - ai * pxi + xr;
            float nxi = ar * pxi + ai * pxr + xi;
            ar = nar; ai = nai; xr = nxr; xi = nxi;
        }
    }

    float ear = __shfl_up(ar, 1u, 64);
    float eai = __shfl_up(ai, 1u, 64);
    float exr = __shfl_up(xr, 1u, 64);
    float exi = __shfl_up(xi, 1u, 64);
    if (lane == 0) { ear = 1.f; eai = 0.f; exr = 0.f; exi = 0.f; }

#pragma unroll
    for (int m = 0; m < NTPL; ++m) {
        seed[((size_t)b * NT + lane * NTPL + m) * DIM + d] =
            make_float2(exr, exi);
        float nar = v[m].x * ear - v[m].y * eai;
        float nai = v[m].x * eai + v[m].y * ear;
        float nxr = v[m].x * exr - v[m].y * exi + v[m].z;
        float nxi = v[m].x * exi + v[m].y * exr + v[m].w;
        ear = nar; eai = nai; exr = nxr; exi = nxi;
    }
}

// ---------------------------------------------------------------------------
// Kernel 3 (R14 form): float2 seed, plain float4 stores.
// ---------------------------------------------------------------------------
template <int NT, int T>
__global__ __launch_bounds__(256, 8) void k_apply(
    const float* __restrict__ Ar, const float* __restrict__ Ai,
    const float* __restrict__ Xr, const float* __restrict__ Xi,
    const float2* __restrict__ seed, float* __restrict__ outf)
{
    int half = threadIdx.x >> 7;
    int wl   = threadIdx.x & 127;
    int tile = blockIdx.x * 2 + half;
    int b = tile / NT;
    int j = tile - b * NT;
    int d = wl * 2;

    float yr[2], yi[2];
    size_t o = ((size_t)b * NT + j) * DIM + d;
    {
        float2 s0 = seed[o];
        float2 s1 = seed[o + 1];
        yr[0] = s0.x; yi[0] = s0.y;
        yr[1] = s1.x; yi[1] = s1.y;
    }

    size_t base = ((size_t)b * SEQ + (size_t)j * T) * DIM + d;

#pragma unroll
    for (int t = 0; t < T; ++t) {
        size_t idx = base + (size_t)t * DIM;
        float2 a_re = *(const float2*)(Ar + idx);
        float2 a_im = *(const float2*)(Ai + idx);
        float2 x_re = *(const float2*)(Xr + idx);
        float2 x_im = *(const float2*)(Xi + idx);
        const float* par = (const float*)&a_re;
        const float* pai = (const float*)&a_im;
        const float* pxr = (const float*)&x_re;
        const float* pxi = (const float*)&x_im;
#pragma unroll
        for (int k = 0; k < 2; ++k) {
            float nyr = par[k] * yr[k] - pai[k] * yi[k] + pxr[k];
            float nyi = par[k] * yi[k] + pai[k] * yr[k] + pxi[k];
            yr[k] = nyr; yi[k] = nyi;
        }
        *(float4*)(outf + 2 * idx) = make_float4(yr[0], yi[0], yr[1], yi[1]);
    }
}

// ===========================================================================
// Fallback 3-kernel path (small workspace) — NT=64, self-contained.
// ===========================================================================
template <int NT, int T>
__global__ __launch_bounds__(256) void k_tile_agg_fb(
    const float* __restrict__ Ar, const float* __restrict__ Ai,
    const float* __restrict__ Xr, const float* __restrict__ Xi,
    float4* __restrict__ agg)
{
    int wave = threadIdx.x >> 6;
    int lane = threadIdx.x & 63;
    int tile = blockIdx.x * 4 + wave;
    int b = tile / NT;
    int j = tile - b * NT;
    int d = lane * 4;

    size_t base = ((size_t)b * SEQ + (size_t)j * T) * DIM + d;

    float pr[4], pi[4], yr[4], yi[4];
#pragma unroll
    for (int k = 0; k < 4; ++k) { pr[k] = 1.f; pi[k] = 0.f; yr[k] = 0.f; yi[k] = 0.f; }

#pragma unroll 4
    for (int t = 0; t < T; ++t) {
        size_t idx = base + (size_t)t * DIM;
        float4 a_re = *(const float4*)(Ar + idx);
        float4 a_im = *(const float4*)(Ai + idx);
        float4 x_re = *(const float4*)(Xr + idx);
        float4 x_im = *(const float4*)(Xi + idx);
        const float* par = (const float*)&a_re;
        const float* pai = (const float*)&a_im;
        const float* pxr = (const float*)&x_re;
        const float* pxi = (const float*)&x_im;
#pragma unroll
        for (int k = 0; k < 4; ++k) {
            float a_r = par[k], a_i = pai[k];
            float npr = a_r * pr[k] - a_i * pi[k];
            float npi = a_r * pi[k] + a_i * pr[k];
            pr[k] = npr; pi[k] = npi;
            float nyr = a_r * yr[k] - a_i * yi[k] + pxr[k];
            float nyi = a_r * yi[k] + a_i * yr[k] + pxi[k];
            yr[k] = nyr; yi[k] = nyi;
        }
    }

    size_t o = ((size_t)b * NT + j) * DIM + d;
#pragma unroll
    for (int k = 0; k < 4; ++k)
        agg[o + k] = make_float4(pr[k], pi[k], yr[k], yi[k]);
}

template <int NT>
__global__ __launch_bounds__(256) void k_scan_agg_fb(float4* __restrict__ agg)
{
    constexpr int NTPL = NT / 64;
    int lane = threadIdx.x & 63;
    int col  = blockIdx.x * 4 + (threadIdx.x >> 6);
    int b = col >> 8;
    int d = col & 255;

    float4 v[NTPL];
    float lar = 1.f, lai = 0.f, lxr = 0.f, lxi = 0.f;
#pragma unroll
    for (int m = 0; m < NTPL; ++m) {
        v[m] = agg[((size_t)b * NT + lane * NTPL + m) * DIM + d];
        float nar = v[m].x * lar - v[m].y * lai;
        float nai = v[m].x * lai + v[m].y * lar;
        float nxr = v[m].x * lxr - v[m].y * lxi + v[m].z;
        float nxi = v[m].x * lxi + v[m].y * lxr + v[m].w;
        lar = nar; lai = nai; lxr = nxr; lxi = nxi;
    }

    float ar = lar, ai = lai, xr = lxr, xi = lxi;
#pragma unroll
    for (int off = 1; off < 64; off <<= 1) {
        float par = __shfl_up(ar, (unsigned)off, 64);
        float pai = __shfl_up(ai, (unsigned)off, 64);
        float pxr = __shfl_up(xr, (unsigned)off, 64);
        float pxi = __shfl_up(xi, (unsigned)off, 64);
        if (lane >= off) {
            float nar = ar * par - ai * pai;
            float nai = ar * pai + ai * par;
            float nxr = ar * pxr - ai * pxi + xr;
            float nxi = ar * pxi + ai * pxr + xi;
            ar = nar; ai = nai; xr = nxr; xi = nxi;
        }
    }

    float ear = __shfl_up(ar, 1u, 64);
    float eai = __shfl_up(ai, 1u, 64);
    float exr = __shfl_up(xr, 1u, 64);
    float exi = __shfl_up(xi, 1u, 64);
    if (lane == 0) { ear = 1.f; eai = 0.f; exr = 0.f; exi = 0.f; }

#pragma unroll
    for (int m = 0; m < NTPL; ++m) {
        agg[((size_t)b * NT + lane * NTPL + m) * DIM + d] =
            make_float4(exr, exi, 0.f, 0.f);
        float nar = v[m].x * ear - v[m].y * eai;
        float nai = v[m].x * eai + v[m].y * ear;
        float nxr = v[m].x * exr - v[m].y * exi + v[m].z;
        float nxi = v[m].x * exi + v[m].y * exr + v[m].w;
        ear = nar; eai = nai; exr = nxr; exi = nxi;
    }
}

template <int NT, int T>
__global__ __launch_bounds__(256, 8) void k_apply_fb(
    const float* __restrict__ Ar, const float* __restrict__ Ai,
    const float* __restrict__ Xr, const float* __restrict__ Xi,
    const float4* __restrict__ agg, float* __restrict__ outf)
{
    int half = threadIdx.x >> 7;
    int wl   = threadIdx.x & 127;
    int tile = blockIdx.x * 2 + half;
    int b = tile / NT;
    int j = tile - b * NT;
    int d = wl * 2;

    float yr[2], yi[2];
    size_t o = ((size_t)b * NT + j) * DIM + d;
    {
        float4 p0 = agg[o];
        float4 p1 = agg[o + 1];
        yr[0] = p0.x; yi[0] = p0.y;
        yr[1] = p1.x; yi[1] = p1.y;
    }

    size_t base = ((size_t)b * SEQ + (size_t)j * T) * DIM + d;

#pragma unroll
    for (int t = 0; t < T; ++t) {
        size_t idx = base + (size_t)t * DIM;
        float2 a_re = *(const float2*)(Ar + idx);
        float2 a_im = *(const float2*)(Ai + idx);
        float2 x_re = *(const float2*)(Xr + idx);
        float2 x_im = *(const float2*)(Xi + idx);
        const float* par = (const float*)&a_re;
        const float* pai = (const float*)&a_im;
        const float* pxr = (const float*)&x_re;
        const float* pxi = (const float*)&x_im;
#pragma unroll
        for (int k = 0; k < 2; ++k) {
            float nyr = par[k] * yr[k] - pai[k] * yi[k] + pxr[k];
            float nyi = par[k] * yi[k] + pai[k] * yr[k] + pxi[k];
            yr[k] = nyr; yi[k] = nyi;
        }
        *(float4*)(outf + 2 * idx) = make_float4(yr[0], yi[0], yr[1], yi[1]);
    }
}

extern "C" void kernel_launch(void* const* d_in, const int* in_sizes, int n_in,
                              void* d_out, int out_size, void* d_ws, size_t ws_size,
                              hipStream_t stream)
{
    const float* Ar = (const float*)d_in[0];
    const float* Ai = (const float*)d_in[1];
    const float* Xr = (const float*)d_in[2];
    const float* Xi = (const float*)d_in[3];
    float* outf = (float*)d_out;

    dim3 block(256);

    if (ws_size >= AGG_BYTES + SEED_BYTES) {
        constexpr int NT = NT_MAIN, T = T_MAIN;        // 256 / 16
        float4* agg  = (float4*)d_ws;
        float2* seed = (float2*)((char*)d_ws + AGG_BYTES);
        dim3 gridP(NSUB_TOT / NSUB_BLK);               // 1024 blocks, 4/CU
        dim3 grid3((BATCH * NT) / 2);                  // k3: 2 waves/tile
        k_tile_agg_pipe<<<gridP, block, 0, stream>>>(Ar, Ai, Xr, Xi, agg);
        k_scan_agg<NT><<<(BATCH * DIM) / 4, block, 0, stream>>>(agg, seed);
        k_apply<NT, T><<<grid3, block, 0, stream>>>(Ar, Ai, Xr, Xi, seed, outf);
    } else {
        constexpr int NT = 64, T = SEQ / 64;
        float4* agg = (float4*)d_ws;
        dim3 grid1((BATCH * NT) / 4);
        dim3 grid3((BATCH * NT) / 2);
        k_tile_agg_fb<NT, T><<<grid1, block, 0, stream>>>(Ar, Ai, Xr, Xi, agg);
        k_scan_agg_fb<NT><<<(BATCH * DIM) / 4, block, 0, stream>>>(agg);
        k_apply_fb<NT, T><<<grid3, block, 0, stream>>>(Ar, Ai, Xr, Xi, agg, outf);
    }
}